// Round 4
// baseline (2910.002 us; speedup 1.0000x reference)
//
#include <hip/hip_runtime.h>
#include <hip/hip_bf16.h>
#include <stdint.h>

// Problem constants (LLAMA2-ish block, L=2, B=1)
#define L_  2
#define D_  2048
#define H_  16
#define HD_ 128
#define FF_ 8192
#define V_  32000
#define S_  2048

typedef __attribute__((ext_vector_type(8))) short s8v;   // 8 x bf16 (4 VGPR) MFMA frag
typedef __attribute__((ext_vector_type(4))) short s4v;   // 4 x bf16 store
typedef __attribute__((ext_vector_type(4))) float f4v;   // MFMA C/D frag

__device__ __forceinline__ unsigned short f2bf(float x) {
  unsigned int u = __float_as_uint(x);
  u += 0x7fffu + ((u >> 16) & 1u);   // RNE
  return (unsigned short)(u >> 16);
}

__device__ __forceinline__ void gload16(const void* g, void* l) {
  // async global->LDS, 16B per lane; LDS dest = wave-uniform base + lane*16
  __builtin_amdgcn_global_load_lds((__attribute__((address_space(1))) const void*)g,
                                   (__attribute__((address_space(3))) void*)l, 16, 0, 0);
}

// ---------------------------------------------------------------------------
// Tiled transpose + fp32 -> bf16 convert:  dst[c][r] = bf16(src[r][c])
// grid: (cols/32, rows/32, Z); block 256
// ---------------------------------------------------------------------------
__global__ __launch_bounds__(256) void k_transpose(
    const float* __restrict__ src, unsigned short* __restrict__ dst,
    int srcld, int dstld, size_t src_z, size_t dst_z)
{
  __shared__ float ts[32][33];
  src += blockIdx.z * src_z;
  dst += blockIdx.z * dst_z;
  const int t  = threadIdx.x;
  const int r0 = blockIdx.y * 32, c0 = blockIdx.x * 32;
  const int lr = t >> 3, lc = (t & 7) * 4;
  float4 v = *(const float4*)(src + (size_t)(r0 + lr) * srcld + c0 + lc);
  ts[lr][lc + 0] = v.x; ts[lr][lc + 1] = v.y; ts[lr][lc + 2] = v.z; ts[lr][lc + 3] = v.w;
  __syncthreads();
  const int oc = t >> 3, orr = (t & 7) * 4;
  s4v o;
  o[0] = (short)f2bf(ts[orr + 0][oc]);
  o[1] = (short)f2bf(ts[orr + 1][oc]);
  o[2] = (short)f2bf(ts[orr + 2][oc]);
  o[3] = (short)f2bf(ts[orr + 3][oc]);
  *(s4v*)(dst + (size_t)(c0 + oc) * dstld + r0 + orr) = o;
}

// ---------------------------------------------------------------------------
// RMSNorm: out_bf16[row][:] = x*rsqrt(mean(x^2)+eps)*w ; one block per row
// ---------------------------------------------------------------------------
__global__ __launch_bounds__(256) void k_rmsnorm(
    const float* __restrict__ x, const float* __restrict__ w,
    unsigned short* __restrict__ out)
{
  const int row = blockIdx.x, tid = threadIdx.x;
  const float4* x4 = (const float4*)(x + (size_t)row * D_);
  const float4* w4 = (const float4*)w;
  float4 v0 = x4[tid], v1 = x4[tid + 256];
  float s = v0.x*v0.x + v0.y*v0.y + v0.z*v0.z + v0.w*v0.w
          + v1.x*v1.x + v1.y*v1.y + v1.z*v1.z + v1.w*v1.w;
  #pragma unroll
  for (int o = 32; o; o >>= 1) s += __shfl_xor(s, o);
  __shared__ float red[4];
  if ((tid & 63) == 0) red[tid >> 6] = s;
  __syncthreads();
  float rs = rsqrtf((red[0] + red[1] + red[2] + red[3]) * (1.0f / D_) + 1e-6f);
  float4 wv = w4[tid];
  s4v o4;
  o4[0] = (short)f2bf(v0.x * rs * wv.x); o4[1] = (short)f2bf(v0.y * rs * wv.y);
  o4[2] = (short)f2bf(v0.z * rs * wv.z); o4[3] = (short)f2bf(v0.w * rs * wv.w);
  *(s4v*)(out + (size_t)row * D_ + tid * 4) = o4;
  wv = w4[tid + 256];
  o4[0] = (short)f2bf(v1.x * rs * wv.x); o4[1] = (short)f2bf(v1.y * rs * wv.y);
  o4[2] = (short)f2bf(v1.z * rs * wv.z); o4[3] = (short)f2bf(v1.w * rs * wv.w);
  *(s4v*)(out + (size_t)row * D_ + (tid + 256) * 4) = o4;
}

// ---------------------------------------------------------------------------
// RoPE tables: cos/sin [S][64]
// ---------------------------------------------------------------------------
__global__ void k_rope_tab(float* __restrict__ cosT, float* __restrict__ sinT)
{
  int idx = blockIdx.x * 256 + threadIdx.x;   // S*64 total
  int s = idx >> 6, d = idx & 63;
  float inv = powf(10000.0f, -(float)d * (1.0f / 64.0f));
  float ang = (float)s * inv;
  cosT[idx] = cosf(ang);
  sinT[idx] = sinf(ang);
}

// ---------------------------------------------------------------------------
// RoPE apply + relayout: src fp32 rows of length srcld, columns
// [colbase, colbase+D) hold the (H,HD) heads -> dst bf16 (H, S, HD)
// ---------------------------------------------------------------------------
__global__ void k_rope(const float* __restrict__ src, unsigned short* __restrict__ dst,
                       const float* __restrict__ cosT, const float* __restrict__ sinT,
                       int srcld, int colbase)
{
  int idx = blockIdx.x * 256 + threadIdx.x;    // h*S*HD + s*HD + d
  int d = idx & 127;
  int s = (idx >> 7) & (S_ - 1);
  int h = idx >> 18;
  float v = src[(size_t)s * srcld + colbase + h * HD_ + d];
  float p = src[(size_t)s * srcld + colbase + h * HD_ + (d ^ 64)];
  float c  = cosT[s * 64 + (d & 63)];
  float sn = sinT[s * 64 + (d & 63)];
  float rot = (d < 64) ? -p : p;
  dst[idx] = f2bf(v * c + rot * sn);
}

// ---------------------------------------------------------------------------
// GEMM: C(MxN) = A(MxK,bf16) * B(KxN)  with B given as Bt = B^T (NxK, bf16).
// 128x128 tile, BK=32, 4 waves, global_load_lds staging (m97 structure).
// EPI: 0 = C fp32 store; 1 = C fp32 +=; 2 = Cb bf16 = silu(aux)*acc
// ---------------------------------------------------------------------------
template <int EPI>
__global__ __launch_bounds__(256) void k_gemm(
    const unsigned short* __restrict__ A, const unsigned short* __restrict__ Bt,
    float* __restrict__ C, unsigned short* __restrict__ Cb,
    const float* __restrict__ aux, int M, int N, int K)
{
  __shared__ short As[128 * 32];
  __shared__ short Bs[128 * 32];
  const int tid  = threadIdx.x;
  const int lane = tid & 63;
  const int w    = tid >> 6;
  const int wr = w >> 1, wc = w & 1;
  const int g = lane >> 4, q = lane & 15;
  const int brow = blockIdx.y * 128;
  const int bcol = blockIdx.x * 128;

  // staging coords: LDS linear (row-major [128][32] bf16) in gload order
  const int srow = w * 16 + (lane >> 2);
  const int sk   = (lane & 3) * 8;
  const unsigned short* gA = A  + (size_t)(brow + srow) * K + sk;
  const unsigned short* gB = Bt + (size_t)(bcol + srow) * K + sk;
  char* lA = (char*)As + w * 1024;
  char* lB = (char*)Bs + w * 1024;

  f4v acc[4][4];
  #pragma unroll
  for (int m = 0; m < 4; m++)
    #pragma unroll
    for (int n = 0; n < 4; n++) acc[m][n] = (f4v){0.f, 0.f, 0.f, 0.f};

  for (int k0 = 0; k0 < K; k0 += 32) {
    gload16(gA + k0,                    lA);
    gload16(gA + (size_t)64 * K + k0,   lA + 4096);
    gload16(gB + k0,                    lB);
    gload16(gB + (size_t)64 * K + k0,   lB + 4096);
    __syncthreads();
    s8v a[4], b[4];
    #pragma unroll
    for (int m = 0; m < 4; m++) a[m] = *(const s8v*)(As + (wr * 64 + m * 16 + q) * 32 + g * 8);
    #pragma unroll
    for (int n = 0; n < 4; n++) b[n] = *(const s8v*)(Bs + (wc * 64 + n * 16 + q) * 32 + g * 8);
    #pragma unroll
    for (int m = 0; m < 4; m++)
      #pragma unroll
      for (int n = 0; n < 4; n++)
        acc[m][n] = __builtin_amdgcn_mfma_f32_16x16x32_bf16(a[m], b[n], acc[m][n], 0, 0, 0);
    __syncthreads();
  }

  #pragma unroll
  for (int m = 0; m < 4; m++) {
    const size_t row0 = (size_t)brow + wr * 64 + m * 16 + g * 4;
    #pragma unroll
    for (int n = 0; n < 4; n++) {
      const size_t col = (size_t)bcol + wc * 64 + n * 16 + q;
      f4v v = acc[m][n];
      #pragma unroll
      for (int i = 0; i < 4; i++) {
        size_t idx = (row0 + i) * (size_t)N + col;
        if (EPI == 0) {
          C[idx] = v[i];
        } else if (EPI == 1) {
          C[idx] += v[i];
        } else {
          float gv = aux[idx];
          float sv = gv / (1.0f + __expf(-gv));   // silu
          Cb[idx] = f2bf(sv * v[i]);
        }
      }
    }
  }
}

// ---------------------------------------------------------------------------
// Flash attention (causal). 1 wave per (16 q-rows, head).
// qb,kb: bf16 (H,S,HD); vT: bf16 (H,HD,S); out: bf16 (S,D).
// Swapped QK^T: S^T = mfma(K,Q) => softmaxed P regs are directly the PV B-frag
// after 8 ds_bpermutes (layout identity derived from C-layout col=lane&15,
// row=(lane>>4)*4+reg).
// ---------------------------------------------------------------------------
__global__ __launch_bounds__(64) void k_flash(
    const unsigned short* __restrict__ qb, const unsigned short* __restrict__ kb,
    const unsigned short* __restrict__ vT, unsigned short* __restrict__ outp)
{
  const int lane = threadIdx.x;
  const int g = lane >> 4, q = lane & 15;
  const int qt = blockIdx.x, h = blockIdx.y;
  const int qrow = qt * 16 + q;
  const unsigned short* Qh = qb + ((size_t)h * S_ + (size_t)qt * 16) * HD_;
  const unsigned short* Kh = kb + (size_t)h * S_ * HD_;
  const unsigned short* Vh = vT + (size_t)h * HD_ * S_;

  s8v qf[4];
  #pragma unroll
  for (int c = 0; c < 4; c++)
    qf[c] = *(const s8v*)(Qh + q * HD_ + c * 32 + g * 8);

  f4v o[8];
  #pragma unroll
  for (int dt = 0; dt < 8; dt++) o[dt] = (f4v){0.f, 0.f, 0.f, 0.f};
  float mrun = -1e30f, lrun = 0.f;
  const float scale = 0.08838834764831845f;  // 1/sqrt(128)
  const int addr0 = (((g & 1) * 2) * 16 + q) * 4;
  const int addr1 = addr0 + 64;
  const bool thi = (g >> 1) != 0;

  for (int jb = 0; jb <= qt * 16 + 15; jb += 32) {
    f4v st[2] = {(f4v){0.f,0.f,0.f,0.f}, (f4v){0.f,0.f,0.f,0.f}};
    #pragma unroll
    for (int t2 = 0; t2 < 2; t2++)
      #pragma unroll
      for (int c = 0; c < 4; c++) {
        s8v kf = *(const s8v*)(Kh + (size_t)(jb + t2 * 16 + q) * HD_ + c * 32 + g * 8);
        st[t2] = __builtin_amdgcn_mfma_f32_16x16x32_bf16(kf, qf[c], st[t2], 0, 0, 0);
      }
    // mask + scale; per-q (lane&15) online softmax across lanes {q,q+16,q+32,q+48}
    float pm = -1e30f;
    float p[2][4];
    #pragma unroll
    for (int t2 = 0; t2 < 2; t2++)
      #pragma unroll
      for (int r = 0; r < 4; r++) {
        int key = jb + t2 * 16 + g * 4 + r;
        float v = st[t2][r] * scale;
        v = (key <= qrow) ? v : -1e30f;
        p[t2][r] = v;
        pm = fmaxf(pm, v);
      }
    pm = fmaxf(pm, __shfl_xor(pm, 16));
    pm = fmaxf(pm, __shfl_xor(pm, 32));
    float mnew  = fmaxf(mrun, pm);
    float alpha = __expf(mrun - mnew);
    float ls = 0.f;
    #pragma unroll
    for (int t2 = 0; t2 < 2; t2++)
      #pragma unroll
      for (int r = 0; r < 4; r++) { float e = __expf(p[t2][r] - mnew); p[t2][r] = e; ls += e; }
    ls += __shfl_xor(ls, 16);
    ls += __shfl_xor(ls, 32);
    lrun = lrun * alpha + ls;
    mrun = mnew;
    #pragma unroll
    for (int dt = 0; dt < 8; dt++) o[dt] *= alpha;

    // pack P (bf16 pairs) and redistribute into the 16x16x32 B-fragment
    unsigned int pk00 = (unsigned)f2bf(p[0][0]) | ((unsigned)f2bf(p[0][1]) << 16);
    unsigned int pk01 = (unsigned)f2bf(p[0][2]) | ((unsigned)f2bf(p[0][3]) << 16);
    unsigned int pk10 = (unsigned)f2bf(p[1][0]) | ((unsigned)f2bf(p[1][1]) << 16);
    unsigned int pk11 = (unsigned)f2bf(p[1][2]) | ((unsigned)f2bf(p[1][3]) << 16);
    int b00 = __builtin_amdgcn_ds_bpermute(addr0, (int)pk00);
    int b01 = __builtin_amdgcn_ds_bpermute(addr0, (int)pk01);
    int b02 = __builtin_amdgcn_ds_bpermute(addr1, (int)pk00);
    int b03 = __builtin_amdgcn_ds_bpermute(addr1, (int)pk01);
    int b10 = __builtin_amdgcn_ds_bpermute(addr0, (int)pk10);
    int b11 = __builtin_amdgcn_ds_bpermute(addr0, (int)pk11);
    int b12 = __builtin_amdgcn_ds_bpermute(addr1, (int)pk10);
    int b13 = __builtin_amdgcn_ds_bpermute(addr1, (int)pk11);
    union { int wds[4]; s8v s; } pf;
    pf.wds[0] = thi ? b10 : b00;
    pf.wds[1] = thi ? b11 : b01;
    pf.wds[2] = thi ? b12 : b02;
    pf.wds[3] = thi ? b13 : b03;

    // O^T += V^T * P^T
    #pragma unroll
    for (int dt = 0; dt < 8; dt++) {
      s8v vf = *(const s8v*)(Vh + (size_t)(dt * 16 + q) * S_ + jb + g * 8);
      o[dt] = __builtin_amdgcn_mfma_f32_16x16x32_bf16(vf, pf.s, o[dt], 0, 0, 0);
    }
  }

  float inv_l = 1.0f / lrun;
  #pragma unroll
  for (int dt = 0; dt < 8; dt++)
    #pragma unroll
    for (int r = 0; r < 4; r++) {
      float val = o[dt][r] * inv_l;
      outp[(size_t)(qt * 16 + q) * D_ + h * HD_ + dt * 16 + g * 4 + r] = f2bf(val);
    }
}

// ---------------------------------------------------------------------------
// Host
// ---------------------------------------------------------------------------
extern "C" void kernel_launch(void* const* d_in, const int* in_sizes, int n_in,
                              void* d_out, int out_size, void* d_ws, size_t ws_size,
                              hipStream_t stream)
{
  (void)in_sizes; (void)n_in; (void)out_size;
  const float* x_in = (const float*)d_in[0];
  const float* Wq   = (const float*)d_in[1];
  const float* Wk   = (const float*)d_in[2];
  const float* Wv   = (const float*)d_in[3];
  const float* Wo   = (const float*)d_in[4];
  const float* Wg   = (const float*)d_in[5];
  const float* Wu   = (const float*)d_in[6];
  const float* Wd   = (const float*)d_in[7];
  const float* ln1  = (const float*)d_in[8];
  const float* ln2  = (const float*)d_in[9];
  const float* lnf  = (const float*)d_in[10];
  const float* Wh   = (const float*)d_in[11];

  char* ws = (char*)d_ws;
  size_t off = 0;
  auto alloc = [&](size_t bytes) -> void* {
    void* p = ws + off;
    off += (bytes + 255) & ~(size_t)255;
    return p;
  };
  // Persistent-per-call buffers
  float*          x     = (float*)         alloc((size_t)S_ * D_ * 4);   // 16 MB
  unsigned short* hbuf  = (unsigned short*)alloc((size_t)S_ * D_ * 2);   // 8 MB
  float*          cosT  = (float*)         alloc((size_t)S_ * 64 * 4);
  float*          sinT  = (float*)         alloc((size_t)S_ * 64 * 4);
  // transposed bf16 weight region (reused per layer; also holds Whead^T).
  // Sized for the larger of {layer weights: 4*D*D + 3*FF*D} and {head: V*D}.
  size_t wT_layer = (size_t)4 * D_ * D_ + 3 * (size_t)FF_ * D_;   // 64M elem
  size_t wT_head  = (size_t)V_ * D_;                              // 65.5M elem
  size_t wT_elems = wT_layer > wT_head ? wT_layer : wT_head;
  unsigned short* wT    = (unsigned short*)alloc(wT_elems * 2);          // 125 MiB
  // Phase-union scratch: attention phase (80 MB) and FFN phase (96 MB) overlaid
  char*           sc    = (char*)          alloc((size_t)96 * 1024 * 1024);
  if (ws_size < off) return;  // workspace too small: bail (output stays poisoned)

  // attention-phase layout within sc
  float*          qkv   = (float*)         (sc);                          // 48 MB: (S, 3*D) fused QKV
  unsigned short* qbb   = (unsigned short*)(sc + (size_t)48 * 1048576);   // 8 MB
  unsigned short* kbb   = (unsigned short*)(sc + (size_t)56 * 1048576);   // 8 MB
  unsigned short* vT    = (unsigned short*)(sc + (size_t)64 * 1048576);   // 8 MB
  unsigned short* attno = (unsigned short*)(sc + (size_t)72 * 1048576);   // 8 MB
  // FFN-phase layout within sc (live only after attn output GEMM retired)
  float*          gbuf  = (float*)         (sc);                          // 64 MB
  unsigned short* act   = (unsigned short*)(sc + (size_t)64 * 1048576);   // 32 MB

  unsigned short* WqT = wT;                       // rows 0..2047   of fused B^T
  unsigned short* WkT = WqT + (size_t)D_ * D_;    // rows 2048..4095
  unsigned short* WvT = WkT + (size_t)D_ * D_;    // rows 4096..6143
  unsigned short* WoT = WvT + (size_t)D_ * D_;
  unsigned short* WgT = WoT + (size_t)D_ * D_;
  unsigned short* WuT = WgT + (size_t)FF_ * D_;
  unsigned short* WdT = WuT + (size_t)FF_ * D_;

  auto tr = [&](const float* s, unsigned short* d, int rows, int cols) {
    dim3 gr(cols / 32, rows / 32, 1);
    hipLaunchKernelGGL(k_transpose, gr, dim3(256), 0, stream, s, d, cols, rows, (size_t)0, (size_t)0);
  };
  auto gemm = [&](int epi, const unsigned short* A, const unsigned short* Bt,
                  float* C, unsigned short* Cb, const float* aux, int M, int N, int K) {
    dim3 gr(N / 128, M / 128, 1);
    if (epi == 0)      hipLaunchKernelGGL(k_gemm<0>, gr, dim3(256), 0, stream, A, Bt, C, Cb, aux, M, N, K);
    else if (epi == 1) hipLaunchKernelGGL(k_gemm<1>, gr, dim3(256), 0, stream, A, Bt, C, Cb, aux, M, N, K);
    else               hipLaunchKernelGGL(k_gemm<2>, gr, dim3(256), 0, stream, A, Bt, C, Cb, aux, M, N, K);
  };

  hipMemcpyAsync(x, x_in, (size_t)S_ * D_ * 4, hipMemcpyDeviceToDevice, stream);
  hipLaunchKernelGGL(k_rope_tab, dim3((S_ * 64) / 256), dim3(256), 0, stream, cosT, sinT);

  for (int l = 0; l < L_; l++) {
    tr(Wq + (size_t)l * D_ * D_,  WqT, D_,  D_);
    tr(Wk + (size_t)l * D_ * D_,  WkT, D_,  D_);
    tr(Wv + (size_t)l * D_ * D_,  WvT, D_,  D_);
    tr(Wo + (size_t)l * D_ * D_,  WoT, D_,  D_);
    tr(Wg + (size_t)l * D_ * FF_, WgT, D_,  FF_);
    tr(Wu + (size_t)l * D_ * FF_, WuT, D_,  FF_);
    tr(Wd + (size_t)l * FF_ * D_, WdT, FF_, D_);

    hipLaunchKernelGGL(k_rmsnorm, dim3(S_), dim3(256), 0, stream, x, ln1 + (size_t)l * D_, hbuf);
    // Fused QKV GEMM: B^T = concat rows of (WqT|WkT|WvT) -> C (S, 3*D)
    gemm(0, hbuf, WqT, qkv, nullptr, nullptr, S_, 3 * D_, D_);

    hipLaunchKernelGGL(k_rope, dim3((H_ * S_ * HD_) / 256), dim3(256), 0, stream,
                       qkv, qbb, cosT, sinT, 3 * D_, 0);
    hipLaunchKernelGGL(k_rope, dim3((H_ * S_ * HD_) / 256), dim3(256), 0, stream,
                       qkv, kbb, cosT, sinT, 3 * D_, D_);
    // v: per-head transpose (S,HD) -> (HD,S) bf16; v lives in columns [2D,3D)
    hipLaunchKernelGGL(k_transpose, dim3(HD_ / 32, S_ / 32, H_), dim3(256), 0, stream,
                       qkv + 2 * D_, vT, 3 * D_, S_, (size_t)HD_, (size_t)HD_ * S_);

    hipLaunchKernelGGL(k_flash, dim3(S_ / 16, H_), dim3(64), 0, stream, qbb, kbb, vT, attno);

    gemm(1, attno, WoT, x, nullptr, nullptr, S_, D_, D_);   // x += attn @ Wo

    hipLaunchKernelGGL(k_rmsnorm, dim3(S_), dim3(256), 0, stream, x, ln2 + (size_t)l * D_, hbuf);
    gemm(0, hbuf, WgT, gbuf, nullptr, nullptr, S_, FF_, D_);          // g = h @ Wg
    gemm(2, hbuf, WuT, nullptr, act, gbuf,    S_, FF_, D_);           // act = silu(g)*u (bf16)
    gemm(1, act, WdT, x, nullptr, nullptr,    S_, D_, FF_);           // x += act @ Wd
  }

  hipLaunchKernelGGL(k_rmsnorm, dim3(S_), dim3(256), 0, stream, x, lnf, hbuf);
  tr(Wh, wT, D_, V_);                                                 // Whead^T into reused region
  gemm(0, hbuf, wT, (float*)d_out, nullptr, nullptr, S_, V_, D_);     // logits
}

// Round 5
// 2852.848 us; speedup vs baseline: 1.0200x; 1.0200x over previous
//
#include <hip/hip_runtime.h>
#include <hip/hip_bf16.h>
#include <stdint.h>

// Problem constants (LLAMA2-ish block, L=2, B=1)
#define L_  2
#define D_  2048
#define H_  16
#define HD_ 128
#define FF_ 8192
#define V_  32000
#define S_  2048

typedef __attribute__((ext_vector_type(8))) short s8v;   // 8 x bf16 (4 VGPR) MFMA frag
typedef __attribute__((ext_vector_type(4))) short s4v;   // 4 x bf16 store
typedef __attribute__((ext_vector_type(4))) float f4v;   // MFMA C/D frag

__device__ __forceinline__ unsigned short f2bf(float x) {
  unsigned int u = __float_as_uint(x);
  u += 0x7fffu + ((u >> 16) & 1u);   // RNE
  return (unsigned short)(u >> 16);
}

__device__ __forceinline__ void gload16(const void* g, void* l) {
  // async global->LDS, 16B per lane; LDS dest = wave-uniform base + lane*16
  __builtin_amdgcn_global_load_lds((__attribute__((address_space(1))) const void*)g,
                                   (__attribute__((address_space(3))) void*)l, 16, 0, 0);
}

// ---------------------------------------------------------------------------
// Tiled transpose + fp32 -> bf16 convert:  dst[c][r] = bf16(src[r][c])
// grid: (cols/32, rows/32, Z); block 256
// ---------------------------------------------------------------------------
__global__ __launch_bounds__(256) void k_transpose(
    const float* __restrict__ src, unsigned short* __restrict__ dst,
    int srcld, int dstld, size_t src_z, size_t dst_z)
{
  __shared__ float ts[32][33];
  src += blockIdx.z * src_z;
  dst += blockIdx.z * dst_z;
  const int t  = threadIdx.x;
  const int r0 = blockIdx.y * 32, c0 = blockIdx.x * 32;
  const int lr = t >> 3, lc = (t & 7) * 4;
  float4 v = *(const float4*)(src + (size_t)(r0 + lr) * srcld + c0 + lc);
  ts[lr][lc + 0] = v.x; ts[lr][lc + 1] = v.y; ts[lr][lc + 2] = v.z; ts[lr][lc + 3] = v.w;
  __syncthreads();
  const int oc = t >> 3, orr = (t & 7) * 4;
  s4v o;
  o[0] = (short)f2bf(ts[orr + 0][oc]);
  o[1] = (short)f2bf(ts[orr + 1][oc]);
  o[2] = (short)f2bf(ts[orr + 2][oc]);
  o[3] = (short)f2bf(ts[orr + 3][oc]);
  *(s4v*)(dst + (size_t)(c0 + oc) * dstld + r0 + orr) = o;
}

// ---------------------------------------------------------------------------
// RMSNorm: out_bf16[row][:] = x*rsqrt(mean(x^2)+eps)*w ; one block per row
// ---------------------------------------------------------------------------
__global__ __launch_bounds__(256) void k_rmsnorm(
    const float* __restrict__ x, const float* __restrict__ w,
    unsigned short* __restrict__ out)
{
  const int row = blockIdx.x, tid = threadIdx.x;
  const float4* x4 = (const float4*)(x + (size_t)row * D_);
  const float4* w4 = (const float4*)w;
  float4 v0 = x4[tid], v1 = x4[tid + 256];
  float s = v0.x*v0.x + v0.y*v0.y + v0.z*v0.z + v0.w*v0.w
          + v1.x*v1.x + v1.y*v1.y + v1.z*v1.z + v1.w*v1.w;
  #pragma unroll
  for (int o = 32; o; o >>= 1) s += __shfl_xor(s, o);
  __shared__ float red[4];
  if ((tid & 63) == 0) red[tid >> 6] = s;
  __syncthreads();
  float rs = rsqrtf((red[0] + red[1] + red[2] + red[3]) * (1.0f / D_) + 1e-6f);
  float4 wv = w4[tid];
  s4v o4;
  o4[0] = (short)f2bf(v0.x * rs * wv.x); o4[1] = (short)f2bf(v0.y * rs * wv.y);
  o4[2] = (short)f2bf(v0.z * rs * wv.z); o4[3] = (short)f2bf(v0.w * rs * wv.w);
  *(s4v*)(out + (size_t)row * D_ + tid * 4) = o4;
  wv = w4[tid + 256];
  o4[0] = (short)f2bf(v1.x * rs * wv.x); o4[1] = (short)f2bf(v1.y * rs * wv.y);
  o4[2] = (short)f2bf(v1.z * rs * wv.z); o4[3] = (short)f2bf(v1.w * rs * wv.w);
  *(s4v*)(out + (size_t)row * D_ + (tid + 256) * 4) = o4;
}

// ---------------------------------------------------------------------------
// RoPE tables: cos/sin [S][64]
// ---------------------------------------------------------------------------
__global__ void k_rope_tab(float* __restrict__ cosT, float* __restrict__ sinT)
{
  int idx = blockIdx.x * 256 + threadIdx.x;   // S*64 total
  int s = idx >> 6, d = idx & 63;
  float inv = powf(10000.0f, -(float)d * (1.0f / 64.0f));
  float ang = (float)s * inv;
  cosT[idx] = cosf(ang);
  sinT[idx] = sinf(ang);
}

// ---------------------------------------------------------------------------
// RoPE apply + relayout: src fp32 rows of length srcld, columns
// [colbase, colbase+D) hold the (H,HD) heads -> dst bf16 (H, S, HD)
// ---------------------------------------------------------------------------
__global__ void k_rope(const float* __restrict__ src, unsigned short* __restrict__ dst,
                       const float* __restrict__ cosT, const float* __restrict__ sinT,
                       int srcld, int colbase)
{
  int idx = blockIdx.x * 256 + threadIdx.x;    // h*S*HD + s*HD + d
  int d = idx & 127;
  int s = (idx >> 7) & (S_ - 1);
  int h = idx >> 18;
  float v = src[(size_t)s * srcld + colbase + h * HD_ + d];
  float p = src[(size_t)s * srcld + colbase + h * HD_ + (d ^ 64)];
  float c  = cosT[s * 64 + (d & 63)];
  float sn = sinT[s * 64 + (d & 63)];
  float rot = (d < 64) ? -p : p;
  dst[idx] = f2bf(v * c + rot * sn);
}

// ---------------------------------------------------------------------------
// GEMM: C(MxN) = A(MxK,bf16) * B(KxN)  with B given as Bt = B^T (NxK, bf16).
// 128x128 tile, BK=32, 4 waves, global_load_lds staging (m97 structure).
// Block mapping: flat id -> XCD-bijective chunk remap (m204) -> M-fastest
// (consecutive work ids share one B-panel => L2 reuse; A stays L3-hot).
// Split-K: gridDim.z slices of K; EPI==1 uses atomicAdd when z>1.
// EPI: 0 = C fp32 store; 1 = C fp32 accumulate; 2 = Cb bf16 = silu(aux)*acc
// ---------------------------------------------------------------------------
template <int EPI>
__global__ __launch_bounds__(256) void k_gemm(
    const unsigned short* __restrict__ A, const unsigned short* __restrict__ Bt,
    float* __restrict__ C, unsigned short* __restrict__ Cb,
    const float* __restrict__ aux, int M, int N, int K)
{
  __shared__ short As[128 * 32];
  __shared__ short Bs[128 * 32];
  const int tid  = threadIdx.x;
  const int lane = tid & 63;
  const int w    = tid >> 6;
  const int wr = w >> 1, wc = w & 1;
  const int g = lane >> 4, q = lane & 15;

  // ---- block remap: XCD-chunked, M-fastest ----
  const int nbx = gridDim.x, nby = gridDim.y;
  const int nwg = nbx * nby;
  const int flat = blockIdx.y * nbx + blockIdx.x;
  const int qd = nwg >> 3, rm = nwg & 7;
  const int xcd = flat & 7, id8 = flat >> 3;
  const int wgid = (xcd < rm ? xcd * (qd + 1) : rm * (qd + 1) + (xcd - rm) * qd) + id8;
  const int brow = (wgid % nby) * 128;
  const int bcol = (wgid / nby) * 128;

  // ---- split-K ----
  const int Ks   = K / gridDim.z;
  const int kbeg = blockIdx.z * Ks;

  // staging coords: LDS linear (row-major [128][32] bf16) in gload order
  const int srow = w * 16 + (lane >> 2);
  const int sk   = (lane & 3) * 8;
  const unsigned short* gA = A  + (size_t)(brow + srow) * K + kbeg + sk;
  const unsigned short* gB = Bt + (size_t)(bcol + srow) * K + kbeg + sk;
  char* lA = (char*)As + w * 1024;
  char* lB = (char*)Bs + w * 1024;

  f4v acc[4][4];
  #pragma unroll
  for (int m = 0; m < 4; m++)
    #pragma unroll
    for (int n = 0; n < 4; n++) acc[m][n] = (f4v){0.f, 0.f, 0.f, 0.f};

  for (int k0 = 0; k0 < Ks; k0 += 32) {
    gload16(gA + k0,                    lA);
    gload16(gA + (size_t)64 * K + k0,   lA + 4096);
    gload16(gB + k0,                    lB);
    gload16(gB + (size_t)64 * K + k0,   lB + 4096);
    __syncthreads();
    s8v a[4], b[4];
    #pragma unroll
    for (int m = 0; m < 4; m++) a[m] = *(const s8v*)(As + (wr * 64 + m * 16 + q) * 32 + g * 8);
    #pragma unroll
    for (int n = 0; n < 4; n++) b[n] = *(const s8v*)(Bs + (wc * 64 + n * 16 + q) * 32 + g * 8);
    #pragma unroll
    for (int m = 0; m < 4; m++)
      #pragma unroll
      for (int n = 0; n < 4; n++)
        acc[m][n] = __builtin_amdgcn_mfma_f32_16x16x32_bf16(a[m], b[n], acc[m][n], 0, 0, 0);
    __syncthreads();
  }

  #pragma unroll
  for (int m = 0; m < 4; m++) {
    const size_t row0 = (size_t)brow + wr * 64 + m * 16 + g * 4;
    #pragma unroll
    for (int n = 0; n < 4; n++) {
      const size_t col = (size_t)bcol + wc * 64 + n * 16 + q;
      f4v v = acc[m][n];
      #pragma unroll
      for (int i = 0; i < 4; i++) {
        size_t idx = (row0 + i) * (size_t)N + col;
        if (EPI == 0) {
          C[idx] = v[i];
        } else if (EPI == 1) {
          if (gridDim.z > 1) atomicAdd(&C[idx], v[i]);
          else               C[idx] += v[i];
        } else {
          float gv = aux[idx];
          float sv = gv / (1.0f + __expf(-gv));   // silu
          Cb[idx] = f2bf(sv * v[i]);
        }
      }
    }
  }
}

// ---------------------------------------------------------------------------
// Flash attention (causal). 1 wave per (16 q-rows, head).
// qb,kb: bf16 (H,S,HD); vT: bf16 (H,HD,S); out: bf16 (S,D).
// Swapped QK^T: S^T = mfma(K,Q) => softmaxed P regs are directly the PV B-frag
// after 8 ds_bpermutes (layout identity derived from C-layout col=lane&15,
// row=(lane>>4)*4+reg).
// ---------------------------------------------------------------------------
__global__ __launch_bounds__(64) void k_flash(
    const unsigned short* __restrict__ qb, const unsigned short* __restrict__ kb,
    const unsigned short* __restrict__ vT, unsigned short* __restrict__ outp)
{
  const int lane = threadIdx.x;
  const int g = lane >> 4, q = lane & 15;
  const int qt = blockIdx.x, h = blockIdx.y;
  const int qrow = qt * 16 + q;
  const unsigned short* Qh = qb + ((size_t)h * S_ + (size_t)qt * 16) * HD_;
  const unsigned short* Kh = kb + (size_t)h * S_ * HD_;
  const unsigned short* Vh = vT + (size_t)h * HD_ * S_;

  s8v qf[4];
  #pragma unroll
  for (int c = 0; c < 4; c++)
    qf[c] = *(const s8v*)(Qh + q * HD_ + c * 32 + g * 8);

  f4v o[8];
  #pragma unroll
  for (int dt = 0; dt < 8; dt++) o[dt] = (f4v){0.f, 0.f, 0.f, 0.f};
  float mrun = -1e30f, lrun = 0.f;
  const float scale = 0.08838834764831845f;  // 1/sqrt(128)
  const int addr0 = (((g & 1) * 2) * 16 + q) * 4;
  const int addr1 = addr0 + 64;
  const bool thi = (g >> 1) != 0;

  for (int jb = 0; jb <= qt * 16 + 15; jb += 32) {
    f4v st[2] = {(f4v){0.f,0.f,0.f,0.f}, (f4v){0.f,0.f,0.f,0.f}};
    #pragma unroll
    for (int t2 = 0; t2 < 2; t2++)
      #pragma unroll
      for (int c = 0; c < 4; c++) {
        s8v kf = *(const s8v*)(Kh + (size_t)(jb + t2 * 16 + q) * HD_ + c * 32 + g * 8);
        st[t2] = __builtin_amdgcn_mfma_f32_16x16x32_bf16(kf, qf[c], st[t2], 0, 0, 0);
      }
    // mask + scale; per-q (lane&15) online softmax across lanes {q,q+16,q+32,q+48}
    float pm = -1e30f;
    float p[2][4];
    #pragma unroll
    for (int t2 = 0; t2 < 2; t2++)
      #pragma unroll
      for (int r = 0; r < 4; r++) {
        int key = jb + t2 * 16 + g * 4 + r;
        float v = st[t2][r] * scale;
        v = (key <= qrow) ? v : -1e30f;
        p[t2][r] = v;
        pm = fmaxf(pm, v);
      }
    pm = fmaxf(pm, __shfl_xor(pm, 16));
    pm = fmaxf(pm, __shfl_xor(pm, 32));
    float mnew  = fmaxf(mrun, pm);
    float alpha = __expf(mrun - mnew);
    float ls = 0.f;
    #pragma unroll
    for (int t2 = 0; t2 < 2; t2++)
      #pragma unroll
      for (int r = 0; r < 4; r++) { float e = __expf(p[t2][r] - mnew); p[t2][r] = e; ls += e; }
    ls += __shfl_xor(ls, 16);
    ls += __shfl_xor(ls, 32);
    lrun = lrun * alpha + ls;
    mrun = mnew;
    #pragma unroll
    for (int dt = 0; dt < 8; dt++) o[dt] *= alpha;

    // pack P (bf16 pairs) and redistribute into the 16x16x32 B-fragment
    unsigned int pk00 = (unsigned)f2bf(p[0][0]) | ((unsigned)f2bf(p[0][1]) << 16);
    unsigned int pk01 = (unsigned)f2bf(p[0][2]) | ((unsigned)f2bf(p[0][3]) << 16);
    unsigned int pk10 = (unsigned)f2bf(p[1][0]) | ((unsigned)f2bf(p[1][1]) << 16);
    unsigned int pk11 = (unsigned)f2bf(p[1][2]) | ((unsigned)f2bf(p[1][3]) << 16);
    int b00 = __builtin_amdgcn_ds_bpermute(addr0, (int)pk00);
    int b01 = __builtin_amdgcn_ds_bpermute(addr0, (int)pk01);
    int b02 = __builtin_amdgcn_ds_bpermute(addr1, (int)pk00);
    int b03 = __builtin_amdgcn_ds_bpermute(addr1, (int)pk01);
    int b10 = __builtin_amdgcn_ds_bpermute(addr0, (int)pk10);
    int b11 = __builtin_amdgcn_ds_bpermute(addr0, (int)pk11);
    int b12 = __builtin_amdgcn_ds_bpermute(addr1, (int)pk10);
    int b13 = __builtin_amdgcn_ds_bpermute(addr1, (int)pk11);
    union { int wds[4]; s8v s; } pf;
    pf.wds[0] = thi ? b10 : b00;
    pf.wds[1] = thi ? b11 : b01;
    pf.wds[2] = thi ? b12 : b02;
    pf.wds[3] = thi ? b13 : b03;

    // O^T += V^T * P^T
    #pragma unroll
    for (int dt = 0; dt < 8; dt++) {
      s8v vf = *(const s8v*)(Vh + (size_t)(dt * 16 + q) * S_ + jb + g * 8);
      o[dt] = __builtin_amdgcn_mfma_f32_16x16x32_bf16(vf, pf.s, o[dt], 0, 0, 0);
    }
  }

  float inv_l = 1.0f / lrun;
  #pragma unroll
  for (int dt = 0; dt < 8; dt++)
    #pragma unroll
    for (int r = 0; r < 4; r++) {
      float val = o[dt][r] * inv_l;
      outp[(size_t)(qt * 16 + q) * D_ + h * HD_ + dt * 16 + g * 4 + r] = f2bf(val);
    }
}

// ---------------------------------------------------------------------------
// Host
// ---------------------------------------------------------------------------
extern "C" void kernel_launch(void* const* d_in, const int* in_sizes, int n_in,
                              void* d_out, int out_size, void* d_ws, size_t ws_size,
                              hipStream_t stream)
{
  (void)in_sizes; (void)n_in; (void)out_size;
  const float* x_in = (const float*)d_in[0];
  const float* Wq   = (const float*)d_in[1];
  const float* Wk   = (const float*)d_in[2];
  const float* Wv   = (const float*)d_in[3];
  const float* Wo   = (const float*)d_in[4];
  const float* Wg   = (const float*)d_in[5];
  const float* Wu   = (const float*)d_in[6];
  const float* Wd   = (const float*)d_in[7];
  const float* ln1  = (const float*)d_in[8];
  const float* ln2  = (const float*)d_in[9];
  const float* lnf  = (const float*)d_in[10];
  const float* Wh   = (const float*)d_in[11];

  char* ws = (char*)d_ws;
  size_t off = 0;
  auto alloc = [&](size_t bytes) -> void* {
    void* p = ws + off;
    off += (bytes + 255) & ~(size_t)255;
    return p;
  };
  // Persistent-per-call buffers
  float*          x     = (float*)         alloc((size_t)S_ * D_ * 4);   // 16 MB
  unsigned short* hbuf  = (unsigned short*)alloc((size_t)S_ * D_ * 2);   // 8 MB
  float*          cosT  = (float*)         alloc((size_t)S_ * 64 * 4);
  float*          sinT  = (float*)         alloc((size_t)S_ * 64 * 4);
  // transposed bf16 weight region (reused per layer; also holds Whead^T).
  size_t wT_layer = (size_t)4 * D_ * D_ + 3 * (size_t)FF_ * D_;   // 64M elem
  size_t wT_head  = (size_t)V_ * D_;                              // 65.5M elem
  size_t wT_elems = wT_layer > wT_head ? wT_layer : wT_head;
  unsigned short* wT    = (unsigned short*)alloc(wT_elems * 2);          // 125 MiB
  // Phase-union scratch: attention phase (80 MB) and FFN phase (96 MB) overlaid
  char*           sc    = (char*)          alloc((size_t)96 * 1024 * 1024);
  if (ws_size < off) return;  // workspace too small: bail (output stays poisoned)

  // attention-phase layout within sc
  float*          qkv   = (float*)         (sc);                          // 48 MB: (S, 3*D) fused QKV
  unsigned short* qbb   = (unsigned short*)(sc + (size_t)48 * 1048576);   // 8 MB
  unsigned short* kbb   = (unsigned short*)(sc + (size_t)56 * 1048576);   // 8 MB
  unsigned short* vT    = (unsigned short*)(sc + (size_t)64 * 1048576);   // 8 MB
  unsigned short* attno = (unsigned short*)(sc + (size_t)72 * 1048576);   // 8 MB
  // FFN-phase layout within sc (live only after attn output GEMM retired)
  float*          gbuf  = (float*)         (sc);                          // 64 MB
  unsigned short* act   = (unsigned short*)(sc + (size_t)64 * 1048576);   // 32 MB

  unsigned short* WqT = wT;                       // rows 0..2047   of fused B^T
  unsigned short* WkT = WqT + (size_t)D_ * D_;    // rows 2048..4095
  unsigned short* WvT = WkT + (size_t)D_ * D_;    // rows 4096..6143
  unsigned short* WoT = WvT + (size_t)D_ * D_;
  unsigned short* WgT = WoT + (size_t)D_ * D_;
  unsigned short* WuT = WgT + (size_t)FF_ * D_;
  unsigned short* WdT = WuT + (size_t)FF_ * D_;

  auto tr = [&](const float* s, unsigned short* d, int rows, int cols) {
    dim3 gr(cols / 32, rows / 32, 1);
    hipLaunchKernelGGL(k_transpose, gr, dim3(256), 0, stream, s, d, cols, rows, (size_t)0, (size_t)0);
  };
  auto gemm = [&](int epi, const unsigned short* A, const unsigned short* Bt,
                  float* C, unsigned short* Cb, const float* aux,
                  int M, int N, int K, int kz) {
    dim3 gr(N / 128, M / 128, kz);
    if (epi == 0)      hipLaunchKernelGGL(k_gemm<0>, gr, dim3(256), 0, stream, A, Bt, C, Cb, aux, M, N, K);
    else if (epi == 1) hipLaunchKernelGGL(k_gemm<1>, gr, dim3(256), 0, stream, A, Bt, C, Cb, aux, M, N, K);
    else               hipLaunchKernelGGL(k_gemm<2>, gr, dim3(256), 0, stream, A, Bt, C, Cb, aux, M, N, K);
  };

  hipMemcpyAsync(x, x_in, (size_t)S_ * D_ * 4, hipMemcpyDeviceToDevice, stream);
  hipLaunchKernelGGL(k_rope_tab, dim3((S_ * 64) / 256), dim3(256), 0, stream, cosT, sinT);

  for (int l = 0; l < L_; l++) {
    tr(Wq + (size_t)l * D_ * D_,  WqT, D_,  D_);
    tr(Wk + (size_t)l * D_ * D_,  WkT, D_,  D_);
    tr(Wv + (size_t)l * D_ * D_,  WvT, D_,  D_);
    tr(Wo + (size_t)l * D_ * D_,  WoT, D_,  D_);
    tr(Wg + (size_t)l * D_ * FF_, WgT, D_,  FF_);
    tr(Wu + (size_t)l * D_ * FF_, WuT, D_,  FF_);
    tr(Wd + (size_t)l * FF_ * D_, WdT, FF_, D_);

    hipLaunchKernelGGL(k_rmsnorm, dim3(S_), dim3(256), 0, stream, x, ln1 + (size_t)l * D_, hbuf);
    // Fused QKV GEMM: B^T = concat rows of (WqT|WkT|WvT) -> C (S, 3*D)
    gemm(0, hbuf, WqT, qkv, nullptr, nullptr, S_, 3 * D_, D_, 1);

    hipLaunchKernelGGL(k_rope, dim3((H_ * S_ * HD_) / 256), dim3(256), 0, stream,
                       qkv, qbb, cosT, sinT, 3 * D_, 0);
    hipLaunchKernelGGL(k_rope, dim3((H_ * S_ * HD_) / 256), dim3(256), 0, stream,
                       qkv, kbb, cosT, sinT, 3 * D_, D_);
    // v: per-head transpose (S,HD) -> (HD,S) bf16; v lives in columns [2D,3D)
    hipLaunchKernelGGL(k_transpose, dim3(HD_ / 32, S_ / 32, H_), dim3(256), 0, stream,
                       qkv + 2 * D_, vT, 3 * D_, S_, (size_t)HD_, (size_t)HD_ * S_);

    hipLaunchKernelGGL(k_flash, dim3(S_ / 16, H_), dim3(64), 0, stream, qbb, kbb, vT, attno);

    gemm(1, attno, WoT, x, nullptr, nullptr, S_, D_, D_, 2);   // x += attn @ Wo (split-K=2)

    hipLaunchKernelGGL(k_rmsnorm, dim3(S_), dim3(256), 0, stream, x, ln2 + (size_t)l * D_, hbuf);
    gemm(0, hbuf, WgT, gbuf, nullptr, nullptr, S_, FF_, D_, 1);       // g = h @ Wg
    gemm(2, hbuf, WuT, nullptr, act, gbuf,    S_, FF_, D_, 1);        // act = silu(g)*u (bf16)
    gemm(1, act, WdT, x, nullptr, nullptr,    S_, D_, FF_, 4);        // x += act @ Wd (split-K=4)
  }

  hipLaunchKernelGGL(k_rmsnorm, dim3(S_), dim3(256), 0, stream, x, lnf, hbuf);
  tr(Wh, wT, D_, V_);                                                 // Whead^T into reused region
  gemm(0, hbuf, wT, (float*)d_out, nullptr, nullptr, S_, V_, D_, 1);  // logits
}